// Round 1
// baseline (207.714 us; speedup 1.0000x reference)
//
#include <hip/hip_runtime.h>
#include <hip/hip_bf16.h>

#define N 8192
#define FIN 512
#define FOUT 64
#define ALPHA 0.2f
#define NEG_BIG -9.0e15f

typedef __attribute__((address_space(1))) const void* gas_cptr;
typedef __attribute__((address_space(3))) void* las_ptr;

// ---------------- K1: Wh = h @ W, fused src/dst = Wh@a1, Wh@a2 --------------
__global__ __launch_bounds__(256) void k_wh(
    const float* __restrict__ h, const float* __restrict__ W,
    const float* __restrict__ a, float* __restrict__ Wh,
    float* __restrict__ src, float* __restrict__ dst) {
  __shared__ float hs[32][68];   // +4 pad: keeps float4 alignment, breaks bank stride
  __shared__ float wsh[64][68];
  const int t = threadIdx.x;
  const int row0 = blockIdx.x * 32;
  const int rg = t >> 4;   // 16 row-groups, 2 rows each
  const int cg = t & 15;   // 16 col-groups, 4 cols each
  float acc[2][4];
#pragma unroll
  for (int i = 0; i < 2; ++i)
#pragma unroll
    for (int q = 0; q < 4; ++q) acc[i][q] = 0.f;

  for (int kc = 0; kc < FIN; kc += 64) {
#pragma unroll
    for (int i = 0; i < 2; ++i) {
      int idx = t + i * 256;
      int r = idx >> 4, c4 = idx & 15;
      *reinterpret_cast<float4*>(&hs[r][c4 * 4]) =
          *reinterpret_cast<const float4*>(&h[(size_t)(row0 + r) * FIN + kc + c4 * 4]);
    }
#pragma unroll
    for (int i = 0; i < 4; ++i) {
      int idx = t + i * 256;
      int r = idx >> 4, c4 = idx & 15;
      *reinterpret_cast<float4*>(&wsh[r][c4 * 4]) =
          *reinterpret_cast<const float4*>(&W[(size_t)(kc + r) * FOUT + c4 * 4]);
    }
    __syncthreads();
#pragma unroll 8
    for (int k = 0; k < 64; ++k) {
      float4 b = *reinterpret_cast<const float4*>(&wsh[k][cg * 4]);
      float a0 = hs[rg * 2 + 0][k];
      float a1 = hs[rg * 2 + 1][k];
      acc[0][0] += a0 * b.x; acc[0][1] += a0 * b.y; acc[0][2] += a0 * b.z; acc[0][3] += a0 * b.w;
      acc[1][0] += a1 * b.x; acc[1][1] += a1 * b.y; acc[1][2] += a1 * b.z; acc[1][3] += a1 * b.w;
    }
    __syncthreads();
  }
#pragma unroll
  for (int i = 0; i < 2; ++i) {
    int row = row0 + rg * 2 + i;
    *reinterpret_cast<float4*>(&Wh[(size_t)row * FOUT + cg * 4]) =
        make_float4(acc[i][0], acc[i][1], acc[i][2], acc[i][3]);
    float s1 = acc[i][0] * a[cg * 4 + 0] + acc[i][1] * a[cg * 4 + 1] +
               acc[i][2] * a[cg * 4 + 2] + acc[i][3] * a[cg * 4 + 3];
    float s2 = acc[i][0] * a[FOUT + cg * 4 + 0] + acc[i][1] * a[FOUT + cg * 4 + 1] +
               acc[i][2] * a[FOUT + cg * 4 + 2] + acc[i][3] * a[FOUT + cg * 4 + 3];
#pragma unroll
    for (int msk = 8; msk >= 1; msk >>= 1) {
      s1 += __shfl_xor(s1, msk);
      s2 += __shfl_xor(s2, msk);
    }
    if (cg == 0) { src[row] = s1; dst[row] = s2; }
  }
}

// ---------------- K2: fused masked softmax + PV (flash style) ---------------
// block: 64 rows x (N/split) j's.  thread: rg=t>>4 owns rows i0..i0+3,
// cg=t&15 owns 4 j's (softmax phase) / 4 f-cols (PV phase).
__global__ __launch_bounds__(256) void k_attn(
    const int* __restrict__ adj, const float* __restrict__ Wh,
    const float* __restrict__ src, const float* __restrict__ dst,
    float* __restrict__ out, float* __restrict__ Opart,
    float* __restrict__ mpart, float* __restrict__ lpart, const int split) {
  __shared__ float wsT[64 * 64];  // Wh tile [j][f], linear (global_load_lds dest)
  __shared__ float pT[64 * 64];   // P^T [j][i]

  const int t = threadIdx.x;
  const int rg = t >> 4;
  const int cg = t & 15;
  const int i0 = rg * 4;
  const int row0 = blockIdx.x * 64;
  const int jlen = N / split;
  const int jbase = blockIdx.y * jlen;
  const int ntiles = jlen / 64;

  float srcv[4];
#pragma unroll
  for (int r = 0; r < 4; ++r) srcv[r] = src[row0 + i0 + r];

  float m[4], l[4], o[4][4];
#pragma unroll
  for (int r = 0; r < 4; ++r) {
    m[r] = NEG_BIG; l[r] = 0.f;
#pragma unroll
    for (int q = 0; q < 4; ++q) o[r][q] = 0.f;
  }

  // prefetch adj + dst for tile 0
  int av[4][4];
  float dv[4];
  {
    const int j0 = jbase;
#pragma unroll
    for (int r = 0; r < 4; ++r) {
      int4 x = *reinterpret_cast<const int4*>(&adj[(size_t)(row0 + i0 + r) * N + j0 + cg * 4]);
      av[r][0] = x.x; av[r][1] = x.y; av[r][2] = x.z; av[r][3] = x.w;
    }
    float4 d4 = *reinterpret_cast<const float4*>(&dst[j0 + cg * 4]);
    dv[0] = d4.x; dv[1] = d4.y; dv[2] = d4.z; dv[3] = d4.w;
  }

  for (int jt = 0; jt < ntiles; ++jt) {
    const int j0 = jbase + jt * 64;

    // stage Wh tile: 64 rows x 64 f = contiguous 16KB from global
    {
      const float* gsrc = &Wh[(size_t)j0 * FOUT];
#pragma unroll
      for (int i = 0; i < 4; ++i) {
        int slot = t + i * 256;  // 16B slots; lane-consecutive => uniform base + lane*16
        __builtin_amdgcn_global_load_lds((gas_cptr)(gsrc + slot * 4),
                                         (las_ptr)(&wsT[slot * 4]), 16, 0, 0);
      }
    }

    // ---- softmax phase (uses prefetched av/dv) ----
    float ev[4][4], tmax[4];
#pragma unroll
    for (int r = 0; r < 4; ++r) {
      tmax[r] = NEG_BIG;
#pragma unroll
      for (int jj = 0; jj < 4; ++jj) {
        float x = srcv[r] + dv[jj];
        float e = x > 0.f ? x : ALPHA * x;
        e = av[r][jj] > 0 ? e : NEG_BIG;
        ev[r][jj] = e;
        tmax[r] = fmaxf(tmax[r], e);
      }
    }
#pragma unroll
    for (int msk = 8; msk >= 1; msk >>= 1)
#pragma unroll
      for (int r = 0; r < 4; ++r) tmax[r] = fmaxf(tmax[r], __shfl_xor(tmax[r], msk));

    float scale[4];
#pragma unroll
    for (int r = 0; r < 4; ++r) {
      float mn = fmaxf(m[r], tmax[r]);
      scale[r] = __expf(m[r] - mn);   // finite: NEG_BIG-NEG_BIG = 0
      m[r] = mn;
    }
    float p[4][4], psum[4];
#pragma unroll
    for (int r = 0; r < 4; ++r) {
      psum[r] = 0.f;
#pragma unroll
      for (int jj = 0; jj < 4; ++jj) {
        float pe = (av[r][jj] > 0) ? __expf(ev[r][jj] - m[r]) : 0.f;
        p[r][jj] = pe;
        psum[r] += pe;
      }
    }
#pragma unroll
    for (int msk = 8; msk >= 1; msk >>= 1)
#pragma unroll
      for (int r = 0; r < 4; ++r) psum[r] += __shfl_xor(psum[r], msk);

#pragma unroll
    for (int r = 0; r < 4; ++r) {
      l[r] = l[r] * scale[r] + psum[r];
#pragma unroll
      for (int q = 0; q < 4; ++q) o[r][q] *= scale[r];
    }
    // write P^T col-major: pT[j][i0..i0+3]
#pragma unroll
    for (int jj = 0; jj < 4; ++jj) {
      *reinterpret_cast<float4*>(&pT[(cg * 4 + jj) * 64 + i0]) =
          make_float4(p[0][jj], p[1][jj], p[2][jj], p[3][jj]);
    }
    __syncthreads();  // pT visible, wsT DMA drained

    // prefetch next tile adj/dst (lands during PV, drained at next barrier)
    {
      const int jn = (jt + 1 < ntiles) ? (j0 + 64) : j0;
#pragma unroll
      for (int r = 0; r < 4; ++r) {
        int4 x = *reinterpret_cast<const int4*>(&adj[(size_t)(row0 + i0 + r) * N + jn + cg * 4]);
        av[r][0] = x.x; av[r][1] = x.y; av[r][2] = x.z; av[r][3] = x.w;
      }
      float4 d4 = *reinterpret_cast<const float4*>(&dst[jn + cg * 4]);
      dv[0] = d4.x; dv[1] = d4.y; dv[2] = d4.z; dv[3] = d4.w;
    }

    // ---- PV phase: o[r][q] += p[i0+r][j] * Wh[j][4cg+q] ----
#pragma unroll 8
    for (int j = 0; j < 64; ++j) {
      float4 pv = *reinterpret_cast<const float4*>(&pT[j * 64 + i0]);
      float4 wv = *reinterpret_cast<const float4*>(&wsT[j * 64 + cg * 4]);
      o[0][0] += pv.x * wv.x; o[0][1] += pv.x * wv.y; o[0][2] += pv.x * wv.z; o[0][3] += pv.x * wv.w;
      o[1][0] += pv.y * wv.x; o[1][1] += pv.y * wv.y; o[1][2] += pv.y * wv.z; o[1][3] += pv.y * wv.w;
      o[2][0] += pv.z * wv.x; o[2][1] += pv.z * wv.y; o[2][2] += pv.z * wv.z; o[2][3] += pv.z * wv.w;
      o[3][0] += pv.w * wv.x; o[3][1] += pv.w * wv.y; o[3][2] += pv.w * wv.z; o[3][3] += pv.w * wv.w;
    }
    __syncthreads();  // pT/wsT reusable
  }

  if (split == 1) {
#pragma unroll
    for (int r = 0; r < 4; ++r) {
      float inv = 1.0f / l[r];
      *reinterpret_cast<float4*>(&out[(size_t)(row0 + i0 + r) * FOUT + cg * 4]) =
          make_float4(o[r][0] * inv, o[r][1] * inv, o[r][2] * inv, o[r][3] * inv);
    }
  } else {
    const int pb = blockIdx.y;
#pragma unroll
    for (int r = 0; r < 4; ++r) {
      *reinterpret_cast<float4*>(&Opart[((size_t)pb * N + row0 + i0 + r) * FOUT + cg * 4]) =
          make_float4(o[r][0], o[r][1], o[r][2], o[r][3]);
      if (cg == 0) {
        mpart[(size_t)pb * N + row0 + i0 + r] = m[r];
        lpart[(size_t)pb * N + row0 + i0 + r] = l[r];
      }
    }
  }
}

// ---------------- K3: combine split partials --------------------------------
__global__ __launch_bounds__(256) void k_combine(
    const float* __restrict__ Opart, const float* __restrict__ mpart,
    const float* __restrict__ lpart, float* __restrict__ out, const int split) {
  int idx = blockIdx.x * 256 + threadIdx.x;  // over N*FOUT
  int row = idx >> 6;
  int f = idx & 63;
  float mmax = -3.0e38f;
  for (int k = 0; k < split; ++k) mmax = fmaxf(mmax, mpart[(size_t)k * N + row]);
  float num = 0.f, den = 0.f;
  for (int k = 0; k < split; ++k) {
    float al = __expf(mpart[(size_t)k * N + row] - mmax);
    num += al * Opart[((size_t)k * N + row) * FOUT + f];
    den += al * lpart[(size_t)k * N + row];
  }
  out[idx] = num / den;
}

// ---------------- launcher ---------------------------------------------------
extern "C" void kernel_launch(void* const* d_in, const int* in_sizes, int n_in,
                              void* d_out, int out_size, void* d_ws, size_t ws_size,
                              hipStream_t stream) {
  const float* h = (const float*)d_in[0];
  const int* adj = (const int*)d_in[1];
  const float* W = (const float*)d_in[2];
  const float* a = (const float*)d_in[3];
  float* out = (float*)d_out;

  // workspace carve (floats)
  const size_t whN = (size_t)N * FOUT;
  float* ws_f = (float*)d_ws;
  float* Wh = ws_f;
  float* srcb = Wh + whN;
  float* dstb = srcb + N;
  float* Opart = dstb + N;

  const size_t base_f = whN + 2 * (size_t)N;
  int split = 8;
  while (split > 1 &&
         (base_f + (size_t)split * (whN + 2 * (size_t)N)) * 4 > ws_size)
    split >>= 1;

  float* mpart = Opart + (size_t)split * whN;
  float* lpart = mpart + (size_t)split * N;

  k_wh<<<dim3(N / 32), 256, 0, stream>>>(h, W, a, Wh, srcb, dstb);
  k_attn<<<dim3(N / 64, split), 256, 0, stream>>>(adj, Wh, srcb, dstb, out,
                                                  Opart, mpart, lpart, split);
  if (split > 1)
    k_combine<<<dim3((N * FOUT) / 256), 256, 0, stream>>>(Opart, mpart, lpart,
                                                          out, split);
}

// Round 2
// 110.576 us; speedup vs baseline: 1.8785x; 1.8785x over previous
//
#include <hip/hip_runtime.h>
#include <hip/hip_bf16.h>

#define N 8192
#define FIN 512
#define FOUT 64
#define L2E 1.44269504089f

typedef __attribute__((address_space(1))) const void* gas_cptr;
typedef __attribute__((address_space(3))) void* las_ptr;
typedef float f32x4 __attribute__((ext_vector_type(4)));
typedef short bf16x8 __attribute__((ext_vector_type(8)));

#if __has_builtin(__builtin_amdgcn_exp2f)
#define EXP2(x) __builtin_amdgcn_exp2f(x)
#else
#define EXP2(x) exp2f(x)
#endif

static __device__ __forceinline__ unsigned short f2bf_rne(float f) {
  unsigned u = __float_as_uint(f);
  u += 0x7FFFu + ((u >> 16) & 1u);
  return (unsigned short)(u >> 16);
}
static __device__ __forceinline__ unsigned fkey(float f) {
  unsigned u = __float_as_uint(f);
  return (u & 0x80000000u) ? ~u : (u | 0x80000000u);
}

// ---- K1: WhT(bf16) = (h @ W)^T, src2/dst2 = (Wh@a1,Wh@a2)*log2e, dmax key --
__global__ __launch_bounds__(256) void k_wh(
    const float* __restrict__ h, const float* __restrict__ W,
    const float* __restrict__ a, unsigned short* __restrict__ WhT,
    float* __restrict__ src2, float* __restrict__ dst2,
    unsigned* __restrict__ dmaxk) {
  __shared__ float hs[32][68];
  __shared__ float wsh[64][68];
  const int t = threadIdx.x;
  const int row0 = blockIdx.x * 32;
  const int rg = t >> 4;
  const int cg = t & 15;
  float acc[2][4];
#pragma unroll
  for (int i = 0; i < 2; ++i)
#pragma unroll
    for (int q = 0; q < 4; ++q) acc[i][q] = 0.f;

  for (int kc = 0; kc < FIN; kc += 64) {
#pragma unroll
    for (int i = 0; i < 2; ++i) {
      int idx = t + i * 256;
      int r = idx >> 4, c4 = idx & 15;
      *reinterpret_cast<float4*>(&hs[r][c4 * 4]) =
          *reinterpret_cast<const float4*>(&h[(size_t)(row0 + r) * FIN + kc + c4 * 4]);
    }
#pragma unroll
    for (int i = 0; i < 4; ++i) {
      int idx = t + i * 256;
      int r = idx >> 4, c4 = idx & 15;
      *reinterpret_cast<float4*>(&wsh[r][c4 * 4]) =
          *reinterpret_cast<const float4*>(&W[(size_t)(kc + r) * FOUT + c4 * 4]);
    }
    __syncthreads();
#pragma unroll 8
    for (int k = 0; k < 64; ++k) {
      float4 b = *reinterpret_cast<const float4*>(&wsh[k][cg * 4]);
      float a0 = hs[rg * 2 + 0][k];
      float a1 = hs[rg * 2 + 1][k];
      acc[0][0] += a0 * b.x; acc[0][1] += a0 * b.y; acc[0][2] += a0 * b.z; acc[0][3] += a0 * b.w;
      acc[1][0] += a1 * b.x; acc[1][1] += a1 * b.y; acc[1][2] += a1 * b.z; acc[1][3] += a1 * b.w;
    }
    __syncthreads();
  }

  float s2l[2];
#pragma unroll
  for (int i = 0; i < 2; ++i) {
    int row = row0 + rg * 2 + i;
    float s1 = acc[i][0] * a[cg * 4 + 0] + acc[i][1] * a[cg * 4 + 1] +
               acc[i][2] * a[cg * 4 + 2] + acc[i][3] * a[cg * 4 + 3];
    float s2 = acc[i][0] * a[FOUT + cg * 4 + 0] + acc[i][1] * a[FOUT + cg * 4 + 1] +
               acc[i][2] * a[FOUT + cg * 4 + 2] + acc[i][3] * a[FOUT + cg * 4 + 3];
#pragma unroll
    for (int msk = 8; msk >= 1; msk >>= 1) {
      s1 += __shfl_xor(s1, msk);
      s2 += __shfl_xor(s2, msk);
    }
    s1 *= L2E; s2 *= L2E;
    if (cg == 0) { src2[row] = s1; dst2[row] = s2; }
    s2l[i] = s2;
  }
  // WhT[c][row] bf16, pack 2 consecutive rows
#pragma unroll
  for (int q = 0; q < 4; ++q) {
    ushort2 pr = make_ushort2(f2bf_rne(acc[0][q]), f2bf_rne(acc[1][q]));
    *reinterpret_cast<ushort2*>(&WhT[(size_t)(cg * 4 + q) * N + row0 + rg * 2]) = pr;
  }
  float wmax = fmaxf(s2l[0], s2l[1]);
#pragma unroll
  for (int msk = 1; msk <= 32; msk <<= 1) wmax = fmaxf(wmax, __shfl_xor(wmax, msk));
  if ((t & 63) == 0) atomicMax(dmaxk, fkey(wmax));
}

// ---- K2: fused masked softmax (fixed bound, no rescale) + bf16 MFMA PV ----
__global__ __launch_bounds__(256) void k_attn(
    const int* __restrict__ adj, const unsigned short* __restrict__ WhT,
    const float* __restrict__ src2, const float* __restrict__ dst2,
    const unsigned* __restrict__ dmaxk, float* __restrict__ out,
    float* __restrict__ Opart, float* __restrict__ lpart, const int split) {
  __shared__ __attribute__((aligned(16))) unsigned short whs[64 * 64];  // [f][j] swz
  __shared__ __attribute__((aligned(16))) unsigned short pbs[64 * 64];  // [i][j] swz

  const int t = threadIdx.x;
  const int w = t >> 6;
  const int ll = t & 63;
  const int rg = t >> 4;
  const int cg = t & 15;
  const int i0 = rg * 4;
  const int row0 = blockIdx.x * 64;
  const int jlen = N / split;
  const int jbase = blockIdx.y * jlen;
  const int ntiles = jlen / 64;

  unsigned kk = dmaxk[0];
  float dmax2 = (kk & 0x80000000u) ? __uint_as_float(kk & 0x7FFFFFFFu)
                                   : __uint_as_float(~kk);

  float s2v[4], m2[4], l[4];
#pragma unroll
  for (int r = 0; r < 4; ++r) {
    s2v[r] = src2[row0 + i0 + r];
    float x = s2v[r] + dmax2;
    m2[r] = fmaxf(x, 0.2f * x);
    l[r] = 0.f;
  }

  f32x4 acc[4];
#pragma unroll
  for (int c = 0; c < 4; ++c) acc[c] = (f32x4){0.f, 0.f, 0.f, 0.f};

  // prefetch adj + dst2 for tile 0
  int av[4][4];
  float dv[4];
  {
    const int j0 = jbase;
#pragma unroll
    for (int r = 0; r < 4; ++r) {
      int4 x = *reinterpret_cast<const int4*>(&adj[(size_t)(row0 + i0 + r) * N + j0 + cg * 4]);
      av[r][0] = x.x; av[r][1] = x.y; av[r][2] = x.z; av[r][3] = x.w;
    }
    float4 d4 = *reinterpret_cast<const float4*>(&dst2[j0 + cg * 4]);
    dv[0] = d4.x; dv[1] = d4.y; dv[2] = d4.z; dv[3] = d4.w;
  }

  for (int jt = 0; jt < ntiles; ++jt) {
    const int j0 = jbase + jt * 64;

    // stage WhT tile (bf16, 8KB) with inverse-swizzled global source
#pragma unroll
    for (int i = 0; i < 2; ++i) {
      int slot = t + i * 256;                    // 0..511 16B slots
      int b = slot * 16;                         // dest byte (linear)
      int u = b ^ (((b >> 7) & 7) << 4);         // unswizzled tile byte
      int f = u >> 7;
      int jl = (u & 127) >> 1;
      const unsigned short* gsrc = &WhT[(size_t)f * N + j0 + jl];
      __builtin_amdgcn_global_load_lds((gas_cptr)gsrc,
                                       (las_ptr)((char*)whs + b), 16, 0, 0);
    }

    // ---- softmax phase (log2 domain, fixed bound m2) ----
    float p[4][4];
#pragma unroll
    for (int r = 0; r < 4; ++r) {
#pragma unroll
      for (int jj = 0; jj < 4; ++jj) {
        float x = s2v[r] + dv[jj];
        float e2 = fmaxf(x, 0.2f * x);
        float pe = EXP2(e2 - m2[r]);
        pe = av[r][jj] > 0 ? pe : 0.f;
        p[r][jj] = pe;
        l[r] += pe;
      }
    }
    // write P (bf16, truncation) rows i0..i0+3, cols cg*4..cg*4+3, swizzled
#pragma unroll
    for (int r = 0; r < 4; ++r) {
      unsigned u0 = __float_as_uint(p[r][0]);
      unsigned u1 = __float_as_uint(p[r][1]);
      unsigned u2 = __float_as_uint(p[r][2]);
      unsigned u3 = __float_as_uint(p[r][3]);
      uint2 pk = make_uint2((u0 >> 16) | (u1 & 0xFFFF0000u),
                            (u2 >> 16) | (u3 & 0xFFFF0000u));
      int row = i0 + r;
      int ba = (row << 7) + (cg << 3);
      ba ^= (row & 7) << 4;
      *reinterpret_cast<uint2*>((char*)pbs + ba) = pk;
    }
    __syncthreads();  // whs DMA drained + pbs visible

    // prefetch next tile adj/dst2 (in flight during MFMA)
    {
      const int jn = (jt + 1 < ntiles) ? (j0 + 64) : j0;
#pragma unroll
      for (int r = 0; r < 4; ++r) {
        int4 x = *reinterpret_cast<const int4*>(&adj[(size_t)(row0 + i0 + r) * N + jn + cg * 4]);
        av[r][0] = x.x; av[r][1] = x.y; av[r][2] = x.z; av[r][3] = x.w;
      }
      float4 d4 = *reinterpret_cast<const float4*>(&dst2[jn + cg * 4]);
      dv[0] = d4.x; dv[1] = d4.y; dv[2] = d4.z; dv[3] = d4.w;
    }

    // ---- MFMA PV: wave w owns output rows 16w..16w+15, cols 0..63 ----
    {
      const int lc = ll & 15;
      const int g16 = (ll >> 4) << 4;  // k-group byte offset (8 bf16)
#pragma unroll
      for (int k0 = 0; k0 < 2; ++k0) {
        int arow = 16 * w + lc;
        int ab = (arow << 7) + k0 * 64 + g16;
        ab ^= (arow & 7) << 4;
        bf16x8 afrag = *reinterpret_cast<const bf16x8*>((const char*)pbs + ab);
#pragma unroll
        for (int c = 0; c < 4; ++c) {
          int brow = c * 16 + lc;
          int bb = (brow << 7) + k0 * 64 + g16;
          bb ^= (brow & 7) << 4;
          bf16x8 bfrag = *reinterpret_cast<const bf16x8*>((const char*)whs + bb);
          acc[c] = __builtin_amdgcn_mfma_f32_16x16x32_bf16(afrag, bfrag, acc[c], 0, 0, 0);
        }
      }
    }
    __syncthreads();  // whs/pbs reusable
  }

  // reduce l over the 16 cg lanes (butterfly: all lanes get total)
#pragma unroll
  for (int msk = 8; msk >= 1; msk >>= 1)
#pragma unroll
    for (int r = 0; r < 4; ++r) l[r] += __shfl_xor(l[r], msk);

  const int orow = row0 + 16 * w + ((ll >> 4) << 2);  // + reg
  const int ocol = ll & 15;                           // + 16*c
  if (split == 1) {
#pragma unroll
    for (int c = 0; c < 4; ++c)
#pragma unroll
      for (int q = 0; q < 4; ++q)
        out[(size_t)(orow + q) * FOUT + c * 16 + ocol] = acc[c][q] / l[q];
  } else {
    const int pb = blockIdx.y;
#pragma unroll
    for (int c = 0; c < 4; ++c)
#pragma unroll
      for (int q = 0; q < 4; ++q)
        Opart[((size_t)pb * N + orow + q) * FOUT + c * 16 + ocol] = acc[c][q];
    if (cg == 0) {
#pragma unroll
      for (int r = 0; r < 4; ++r)
        lpart[(size_t)pb * N + row0 + i0 + r] = l[r];
    }
  }
}

// ---- K3: combine split partials (shared m => plain sums) ------------------
__global__ __launch_bounds__(256) void k_combine(
    const float* __restrict__ Opart, const float* __restrict__ lpart,
    float* __restrict__ out, const int split) {
  int idx = blockIdx.x * 256 + threadIdx.x;
  int row = idx >> 6;
  float num = 0.f, den = 0.f;
  for (int k = 0; k < split; ++k) {
    num += Opart[(size_t)k * N * FOUT + idx];
    den += lpart[(size_t)k * N + row];
  }
  out[idx] = num / den;
}

// ---- launcher --------------------------------------------------------------
extern "C" void kernel_launch(void* const* d_in, const int* in_sizes, int n_in,
                              void* d_out, int out_size, void* d_ws, size_t ws_size,
                              hipStream_t stream) {
  const float* h = (const float*)d_in[0];
  const int* adj = (const int*)d_in[1];
  const float* W = (const float*)d_in[2];
  const float* a = (const float*)d_in[3];
  float* out = (float*)d_out;

  unsigned short* WhT = (unsigned short*)d_ws;            // 64*N bf16 = 1MB
  float* src2 = (float*)(WhT + (size_t)FOUT * N);
  float* dst2 = src2 + N;
  unsigned* dmaxk = (unsigned*)(dst2 + N);
  float* Opart = (float*)(dmaxk + 64);                    // padded

  const size_t base_bytes = (size_t)FOUT * N * 2 + 2 * N * 4 + 256;
  int split = 8;
  while (split > 1 &&
         base_bytes + (size_t)split * ((size_t)N * FOUT + N) * 4 > ws_size)
    split >>= 1;
  float* lpart = Opart + (size_t)split * N * FOUT;

  hipMemsetAsync(dmaxk, 0, 4, stream);
  k_wh<<<dim3(N / 32), 256, 0, stream>>>(h, W, a, WhT, src2, dst2, dmaxk);
  k_attn<<<dim3(N / 64, split), 256, 0, stream>>>(adj, WhT, src2, dst2, dmaxk,
                                                  out, Opart, lpart, split);
  if (split > 1)
    k_combine<<<dim3((N * FOUT) / 256), 256, 0, stream>>>(Opart, lpart, out, split);
}

// Round 3
// 107.124 us; speedup vs baseline: 1.9390x; 1.0322x over previous
//
#include <hip/hip_runtime.h>
#include <hip/hip_bf16.h>

#define N 8192
#define FIN 512
#define FOUT 64
#define L2E 1.44269504089f
#define SPLIT 8

typedef __attribute__((address_space(1))) const void* gas_cptr;
typedef __attribute__((address_space(3))) void* las_ptr;
typedef float f32x4 __attribute__((ext_vector_type(4)));
typedef short bf16x8 __attribute__((ext_vector_type(8)));

#if __has_builtin(__builtin_amdgcn_exp2f)
#define EXP2(x) __builtin_amdgcn_exp2f(x)
#else
#define EXP2(x) exp2f(x)
#endif

static __device__ __forceinline__ unsigned short f2bf_rne(float f) {
  unsigned u = __float_as_uint(f);
  u += 0x7FFFu + ((u >> 16) & 1u);
  return (unsigned short)(u >> 16);
}
static __device__ __forceinline__ unsigned fkey(float f) {
  unsigned u = __float_as_uint(f);
  return (u & 0x80000000u) ? ~u : (u | 0x80000000u);
}

// ---- K1: WhT(bf16) = (h @ W)^T via bf16 MFMA; src2/dst2 = (Wh@a)*log2e ----
// grid N/64 blocks, 256 thr. W^T staged once (swizzled bf16, 64KB); h chunks
// are wave-private (each wave stages exactly its 16 MFMA A-rows) -> no
// barriers in the K-loop.
__global__ __launch_bounds__(256) void k_wh(
    const float* __restrict__ h, const float* __restrict__ W,
    const float* __restrict__ a, unsigned short* __restrict__ WhT,
    float* __restrict__ src2, float* __restrict__ dst2,
    unsigned* __restrict__ dmaxk) {
  __shared__ __attribute__((aligned(16))) char wts[64 * 512 * 2];  // [f][k] swz
  __shared__ __attribute__((aligned(16))) char hsb[2][64 * 64 * 2];  // [row][k] swz

  const int t = threadIdx.x;
  const int w = t >> 6;
  const int ll = t & 63;
  const int lc = ll & 15;
  const int row0 = blockIdx.x * 64;

  // ---- stage W^T bf16 swizzled (once) ----
  {
    const int k0 = t * 2;
#pragma unroll
    for (int f4 = 0; f4 < 16; ++f4) {
      float4 x0 = *reinterpret_cast<const float4*>(&W[(size_t)k0 * FOUT + f4 * 4]);
      float4 x1 = *reinterpret_cast<const float4*>(&W[(size_t)(k0 + 1) * FOUT + f4 * 4]);
      const float e0[4] = {x0.x, x0.y, x0.z, x0.w};
      const float e1[4] = {x1.x, x1.y, x1.z, x1.w};
#pragma unroll
      for (int e = 0; e < 4; ++e) {
        int f = f4 * 4 + e;
        int bb = f * 1024 + k0 * 2;
        bb ^= (f & 7) << 4;
        *reinterpret_cast<ushort2*>(wts + bb) =
            make_ushort2(f2bf_rne(e0[e]), f2bf_rne(e1[e]));
      }
    }
  }
  __syncthreads();

  f32x4 acc[4];
#pragma unroll
  for (int c = 0; c < 4; ++c) acc[c] = (f32x4){0.f, 0.f, 0.f, 0.f};

  const int hrow = 16 * w + (ll >> 2);
  const float* hbase = &h[(size_t)(row0 + hrow) * FIN + (ll & 3) * 16];

#define LOADH(dst, kc)                                                        \
  do {                                                                        \
    dst[0] = *reinterpret_cast<const float4*>(hbase + (kc));                  \
    dst[1] = *reinterpret_cast<const float4*>(hbase + (kc) + 4);              \
    dst[2] = *reinterpret_cast<const float4*>(hbase + (kc) + 8);              \
    dst[3] = *reinterpret_cast<const float4*>(hbase + (kc) + 12);             \
  } while (0)

#define WRITEH(buf, src)                                                      \
  do {                                                                        \
    int bb0 = hrow * 128 + (ll & 3) * 32;                                     \
    bb0 ^= (hrow & 7) << 4;                                                   \
    _Pragma("unroll") for (int q = 0; q < 4; ++q) {                           \
      ushort4 u = make_ushort4(f2bf_rne(src[q].x), f2bf_rne(src[q].y),        \
                               f2bf_rne(src[q].z), f2bf_rne(src[q].w));       \
      *reinterpret_cast<ushort4*>(hsb[buf] + (bb0 ^ (q * 8))) = u;            \
    }                                                                         \
  } while (0)

#define MFMA_CHUNK(buf, kcb)                                                  \
  do {                                                                        \
    _Pragma("unroll") for (int k0 = 0; k0 < 2; ++k0) {                        \
      int arow = 16 * w + lc;                                                 \
      int ab = arow * 128 + k0 * 64 + ((ll >> 4) << 4);                       \
      ab ^= (arow & 7) << 4;                                                  \
      bf16x8 af = *reinterpret_cast<const bf16x8*>(hsb[buf] + ab);            \
      _Pragma("unroll") for (int c = 0; c < 4; ++c) {                         \
        int f = c * 16 + lc;                                                  \
        int bb = f * 1024 + (kcb) + k0 * 64 + ((ll >> 4) << 4);               \
        bb ^= (f & 7) << 4;                                                   \
        bf16x8 bfr = *reinterpret_cast<const bf16x8*>(wts + bb);              \
        acc[c] = __builtin_amdgcn_mfma_f32_16x16x32_bf16(af, bfr, acc[c], 0, 0, 0); \
      }                                                                       \
    }                                                                         \
  } while (0)

  float4 ha[4], hb[4];
  LOADH(ha, 0);
#pragma unroll
  for (int c2 = 0; c2 < 4; ++c2) {
    WRITEH(0, ha);
    LOADH(hb, (2 * c2 + 1) * 64);
    MFMA_CHUNK(0, (2 * c2) * 128);
    WRITEH(1, hb);
    if (c2 < 3) LOADH(ha, (2 * c2 + 2) * 64);
    MFMA_CHUNK(1, (2 * c2 + 1) * 128);
  }

  // ---- epilogue: src2/dst2 (log2-scaled), WhT bf16, dmax ----
  float a1v[4], a2v[4];
#pragma unroll
  for (int c = 0; c < 4; ++c) {
    a1v[c] = a[c * 16 + lc];
    a2v[c] = a[FOUT + c * 16 + lc];
  }
  float p1[4], p2[4];
#pragma unroll
  for (int q = 0; q < 4; ++q) {
    p1[q] = acc[0][q] * a1v[0] + acc[1][q] * a1v[1] + acc[2][q] * a1v[2] + acc[3][q] * a1v[3];
    p2[q] = acc[0][q] * a2v[0] + acc[1][q] * a2v[1] + acc[2][q] * a2v[2] + acc[3][q] * a2v[3];
  }
#pragma unroll
  for (int msk = 8; msk >= 1; msk >>= 1)
#pragma unroll
    for (int q = 0; q < 4; ++q) {
      p1[q] += __shfl_xor(p1[q], msk);
      p2[q] += __shfl_xor(p2[q], msk);
    }
#pragma unroll
  for (int q = 0; q < 4; ++q) { p1[q] *= L2E; p2[q] *= L2E; }

  const int r0 = row0 + 16 * w + ((ll >> 4) << 2);
  if (lc == 0) {
#pragma unroll
    for (int q = 0; q < 4; ++q) { src2[r0 + q] = p1[q]; dst2[r0 + q] = p2[q]; }
  }
#pragma unroll
  for (int c = 0; c < 4; ++c) {
    ushort4 u = make_ushort4(f2bf_rne(acc[c][0]), f2bf_rne(acc[c][1]),
                             f2bf_rne(acc[c][2]), f2bf_rne(acc[c][3]));
    *reinterpret_cast<ushort4*>(&WhT[(size_t)(c * 16 + lc) * N + r0]) = u;
  }
  float wm = fmaxf(fmaxf(p2[0], p2[1]), fmaxf(p2[2], p2[3]));
  wm = fmaxf(wm, __shfl_xor(wm, 16));
  wm = fmaxf(wm, __shfl_xor(wm, 32));
  if (ll == 0) atomicMax(dmaxk, fkey(wm));
#undef LOADH
#undef WRITEH
#undef MFMA_CHUNK
}

// ---- K2: fused masked softmax (fixed bound) + bf16 MFMA PV ----------------
// One barrier per tile: whs double-buffered (DMA issued a full tile early);
// pbs rows are wave-private (each wave writes exactly its MFMA A-rows).
__global__ __launch_bounds__(256) void k_attn(
    const int* __restrict__ adj, const unsigned short* __restrict__ WhT,
    const float* __restrict__ src2, const float* __restrict__ dst2,
    const unsigned* __restrict__ dmaxk, float* __restrict__ out,
    float* __restrict__ Opart, float* __restrict__ lpart, const int split) {
  __shared__ __attribute__((aligned(16))) char whs[2 * 8192];  // [f][j] bf16 swz
  __shared__ __attribute__((aligned(16))) char pbs[8192];      // [i][j] bf16 swz

  const int t = threadIdx.x;
  const int w = t >> 6;
  const int ll = t & 63;
  const int rg = t >> 4;
  const int cg = t & 15;
  const int i0 = rg * 4;
  const int row0 = blockIdx.x * 64;
  const int jlen = N / split;
  const int jbase = blockIdx.y * jlen;
  const int ntiles = jlen / 64;

  unsigned kk = dmaxk[0];
  const float dmax2 = (kk & 0x80000000u) ? __uint_as_float(kk & 0x7FFFFFFFu)
                                         : __uint_as_float(~kk);

  float s2v[4], m2[4], l[4];
#pragma unroll
  for (int r = 0; r < 4; ++r) {
    s2v[r] = src2[row0 + i0 + r];
    float x = s2v[r] + dmax2;
    m2[r] = fmaxf(x, 0.2f * x);
    l[r] = 0.f;
  }

  f32x4 acc[4];
#pragma unroll
  for (int c = 0; c < 4; ++c) acc[c] = (f32x4){0.f, 0.f, 0.f, 0.f};

#define STAGE_WHS(buf, j0)                                                    \
  do {                                                                        \
    _Pragma("unroll") for (int i_ = 0; i_ < 2; ++i_) {                        \
      int slot = t + i_ * 256;                                                \
      int b = slot * 16;                                                      \
      int u = b ^ (((b >> 7) & 7) << 4);                                      \
      int f_ = u >> 7;                                                        \
      int jl = (u & 127) >> 1;                                                \
      __builtin_amdgcn_global_load_lds(                                       \
          (gas_cptr)(WhT + (size_t)f_ * N + (j0) + jl),                       \
          (las_ptr)(whs + (buf)*8192 + b), 16, 0, 0);                         \
    }                                                                         \
  } while (0)

#define LOAD_ADJ(AV, DV, j0)                                                  \
  do {                                                                        \
    _Pragma("unroll") for (int r_ = 0; r_ < 4; ++r_) {                        \
      int4 x_ = *reinterpret_cast<const int4*>(                               \
          &adj[(size_t)(row0 + i0 + r_) * N + (j0) + cg * 4]);                \
      AV[r_][0] = x_.x; AV[r_][1] = x_.y; AV[r_][2] = x_.z; AV[r_][3] = x_.w; \
    }                                                                         \
    float4 d_ = *reinterpret_cast<const float4*>(&dst2[(j0) + cg * 4]);       \
    DV[0] = d_.x; DV[1] = d_.y; DV[2] = d_.z; DV[3] = d_.w;                   \
  } while (0)

  int av[4][4], nav[4][4];
  float dv[4], ndv[4];
  STAGE_WHS(0, jbase);
  LOAD_ADJ(av, dv, jbase);

  for (int jt = 0; jt < ntiles; ++jt) {
    const int cur = jt & 1;
    __syncthreads();  // whs[cur] DMA (issued a full tile ago) drained

    if (jt + 1 < ntiles) {
      STAGE_WHS(cur ^ 1, jbase + (jt + 1) * 64);
      LOAD_ADJ(nav, ndv, jbase + (jt + 1) * 64);
    }

    // softmax phase (log2 domain, fixed bound m2)
    float p[4][4];
#pragma unroll
    for (int r = 0; r < 4; ++r) {
#pragma unroll
      for (int jj = 0; jj < 4; ++jj) {
        float x = s2v[r] + dv[jj];
        float e2 = fmaxf(x, 0.2f * x);
        float pe = EXP2(e2 - m2[r]);
        pe = av[r][jj] > 0 ? pe : 0.f;
        p[r][jj] = pe;
        l[r] += pe;
      }
    }
    // pack P rows (wave-private) into pbs, swizzled
#pragma unroll
    for (int r = 0; r < 4; ++r) {
      unsigned u0 = __float_as_uint(p[r][0]);
      unsigned u1 = __float_as_uint(p[r][1]);
      unsigned u2 = __float_as_uint(p[r][2]);
      unsigned u3 = __float_as_uint(p[r][3]);
      uint2 pk = make_uint2((u0 >> 16) | (u1 & 0xFFFF0000u),
                            (u2 >> 16) | (u3 & 0xFFFF0000u));
      int row = i0 + r;
      int ba = (row << 7) + (cg << 3);
      ba ^= (row & 7) << 4;
      *reinterpret_cast<uint2*>(pbs + ba) = pk;
    }

    // MFMA PV (A rows = this wave's pbs rows; B = whs[cur])
    {
      const int lc = ll & 15;
      const int g16 = (ll >> 4) << 4;
#pragma unroll
      for (int k0 = 0; k0 < 2; ++k0) {
        int arow = 16 * w + lc;
        int ab = (arow << 7) + k0 * 64 + g16;
        ab ^= (arow & 7) << 4;
        bf16x8 af = *reinterpret_cast<const bf16x8*>(pbs + ab);
#pragma unroll
        for (int c = 0; c < 4; ++c) {
          int brow = c * 16 + lc;
          int bb = (brow << 7) + k0 * 64 + g16;
          bb ^= (brow & 7) << 4;
          bf16x8 bfr = *reinterpret_cast<const bf16x8*>(whs + cur * 8192 + bb);
          acc[c] = __builtin_amdgcn_mfma_f32_16x16x32_bf16(af, bfr, acc[c], 0, 0, 0);
        }
      }
    }

    if (jt + 1 < ntiles) {
#pragma unroll
      for (int r = 0; r < 4; ++r) {
#pragma unroll
        for (int jj = 0; jj < 4; ++jj) av[r][jj] = nav[r][jj];
        dv[r] = ndv[r];
      }
    }
  }

  // reduce l over the 16 cg lanes
#pragma unroll
  for (int msk = 8; msk >= 1; msk >>= 1)
#pragma unroll
    for (int r = 0; r < 4; ++r) l[r] += __shfl_xor(l[r], msk);

  const int orow = row0 + 16 * w + ((ll >> 4) << 2);
  const int ocol = ll & 15;
  if (split == 1) {
#pragma unroll
    for (int c = 0; c < 4; ++c)
#pragma unroll
      for (int q = 0; q < 4; ++q)
        out[(size_t)(orow + q) * FOUT + c * 16 + ocol] = acc[c][q] / l[q];
  } else {
    const int pb = blockIdx.y;
#pragma unroll
    for (int c = 0; c < 4; ++c)
#pragma unroll
      for (int q = 0; q < 4; ++q)
        Opart[((size_t)pb * N + orow + q) * FOUT + c * 16 + ocol] = acc[c][q];
    if (cg == 0) {
#pragma unroll
      for (int r = 0; r < 4; ++r)
        lpart[(size_t)pb * N + row0 + i0 + r] = l[r];
    }
  }
#undef STAGE_WHS
#undef LOAD_ADJ
}

// ---- K3: combine split partials (shared m => plain sums) ------------------
__global__ __launch_bounds__(256) void k_combine(
    const float* __restrict__ Opart, const float* __restrict__ lpart,
    float* __restrict__ out, const int split) {
  int idx = blockIdx.x * 256 + threadIdx.x;
  int row = idx >> 6;
  float num = 0.f, den = 0.f;
  for (int k = 0; k < split; ++k) {
    num += Opart[(size_t)k * N * FOUT + idx];
    den += lpart[(size_t)k * N + row];
  }
  out[idx] = num / den;
}

// ---- launcher --------------------------------------------------------------
extern "C" void kernel_launch(void* const* d_in, const int* in_sizes, int n_in,
                              void* d_out, int out_size, void* d_ws, size_t ws_size,
                              hipStream_t stream) {
  const float* h = (const float*)d_in[0];
  const int* adj = (const int*)d_in[1];
  const float* W = (const float*)d_in[2];
  const float* a = (const float*)d_in[3];
  float* out = (float*)d_out;

  unsigned short* WhT = (unsigned short*)d_ws;  // 64*N bf16 = 1MB
  float* src2 = (float*)(WhT + (size_t)FOUT * N);
  float* dst2 = src2 + N;
  unsigned* dmaxk = (unsigned*)(dst2 + N);
  float* Opart = (float*)(dmaxk + 64);

  const size_t base_bytes = (size_t)FOUT * N * 2 + 2 * N * 4 + 256;
  int split = SPLIT;
  while (split > 1 &&
         base_bytes + (size_t)split * ((size_t)N * FOUT + N) * 4 > ws_size)
    split >>= 1;
  float* lpart = Opart + (size_t)split * N * FOUT;

  hipMemsetAsync(dmaxk, 0, 4, stream);
  k_wh<<<dim3(N / 64), 256, 0, stream>>>(h, W, a, WhT, src2, dst2, dmaxk);
  k_attn<<<dim3(N / 64, split), 256, 0, stream>>>(adj, WhT, src2, dst2, dmaxk,
                                                  out, Opart, lpart, split);
  if (split > 1)
    k_combine<<<dim3((N * FOUT) / 256), 256, 0, stream>>>(Opart, lpart, out, split);
}